// Round 8
// baseline (300.683 us; speedup 1.0000x reference)
//
#include <hip/hip_runtime.h>
#include <hip/hip_fp16.h>
#include <cstdint>

#define V_N 50000
#define E_N 800000
#define NODE_IN 128
#define EDGE_IN 16
#define HF 128
#define NEG_SLOPE 0.2f
#define NBUCKET 196     // ceil(50000/256) coarse dst buckets (dst>>8)
#define NPART 784       // edge partitions of 1024 for hist/bin
#define NODE_BLKS 1563  // ceil(50000/32)
#define PREP_BLKS 64

// ---- workspace layout (4-byte word offsets) ----
#define OFF_FT    0         // V*64 words (f16 ft, head-major)
#define OFF_EL    3200000   // V*4
#define OFF_ER    3400000   // V*4
#define OFF_ROW   3600000   // V+1 ints
#define OFF_H     3650260   // NBUCKET*NPART ints = 153664 (H[bin][part])
#define OFF_BB    3803928   // NBUCKET+1 ints (bucket bases)
#define OFF_WATT  3804128   // 64
#define OFF_BFRAG 3804192   // 16384 words (16B-aligned)
#define OFF_RECB  3820580   // E*4 words (bucket-grouped records, 16B-aligned)
#define OFF_REC   7020580   // E*4 words (dst-grouped records, 16B-aligned)
// total ~10.2M words = 40.9 MB

typedef short bf16x8 __attribute__((ext_vector_type(8)));
typedef float f32x4 __attribute__((ext_vector_type(4)));

__device__ __forceinline__ unsigned short f2bf(float f) {
    unsigned u = __float_as_uint(f);
    u += 0x7fffu + ((u >> 16) & 1u);   // round-to-nearest-even
    return (unsigned short)(u >> 16);
}
__device__ __forceinline__ unsigned pk2(float lo, float hi) {
    return (unsigned)f2bf(lo) | ((unsigned)f2bf(hi) << 16);
}
__device__ __forceinline__ float bflo(unsigned w) { return __uint_as_float(w << 16); }
__device__ __forceinline__ float bfhi(unsigned w) { return __uint_as_float(w & 0xffff0000u); }

typedef __fp16 fp16x2 __attribute__((ext_vector_type(2)));
__device__ __forceinline__ unsigned pkh2(float a, float b) {
    fp16x2 h = __builtin_amdgcn_cvt_pkrtz(a, b);   // v_cvt_pkrtz_f16_f32
    return __builtin_bit_cast(unsigned, h);
}
__device__ __forceinline__ __half2 u2h(unsigned u) {
    return __builtin_bit_cast(__half2, u);
}
__device__ __forceinline__ unsigned h2u(__half2 h) {
    return __builtin_bit_cast(unsigned, h);
}

// K1: prep (blocks < PREP_BLKS: watt + bfrag) ∥ bucket-hist (LDS, no global
// atomics): partition hb covers edges [hb*1024, hb*1024+1024).
__global__ __launch_bounds__(256) void k_prephist(
    const float* __restrict__ We, const float* __restrict__ attn_e,
    const float* __restrict__ Wn, const float* __restrict__ Wr,
    const int* __restrict__ dst,
    float* __restrict__ watt, unsigned* __restrict__ bfrag,
    int* __restrict__ H)
{
    const int t = threadIdx.x;
    if (blockIdx.x >= PREP_BLKS) {
        int hb = blockIdx.x - PREP_BLKS;
        __shared__ int h[NBUCKET];
        for (int i = t; i < NBUCKET; i += 256) h[i] = 0;
        __syncthreads();
        #pragma unroll
        for (int c = 0; c < 4; c++) {
            int e = hb * 1024 + c * 256 + t;
            if (e < E_N) atomicAdd(&h[dst[e] >> 8], 1);
        }
        __syncthreads();
        for (int i = t; i < NBUCKET; i += 256) H[i * NPART + hb] = h[i];
        return;
    }
    int g = blockIdx.x * 256 + t;
    if (blockIdx.x == 0 && t < 64) {
        int k = t >> 2, hh = t & 3;
        float s = 0.f;
        #pragma unroll
        for (int f = 0; f < 32; f++)
            s += We[k * HF + hh * 32 + f] * attn_e[hh * 32 + f];
        watt[k * 4 + hh] = s;
    }
    // g < 16384 always (64 blocks x 256)
    {
        int c    = g >> 8;
        int lane = (g >> 2) & 63;
        int jp   = g & 3;
        int nt = c >> 2, ks = c & 3;
        int col = nt * 16 + (lane & 15);
        int k   = ks * 32 + (lane >> 4) * 8 + jp * 2;
        const float* W = (col < 128) ? Wn : Wr;
        int cc = col & 127;
        float x0 = W[(size_t)k * 128 + cc];
        float x1 = W[(size_t)(k + 1) * 128 + cc];
        bfrag[g] = pk2(x0, x1);
    }
}

// K2: block 0 = cursor scan (H column scan + bucket bases) ∥ node MFMA.
// Both halves depend only on K1.
__global__ __launch_bounds__(256) void k_nodescan(
    const float* __restrict__ nf, const unsigned* __restrict__ bfragw,
    const float* __restrict__ attn_l, const float* __restrict__ attn_r,
    const float* __restrict__ bias,
    unsigned* __restrict__ ftw, float* __restrict__ el,
    float* __restrict__ er, float* __restrict__ out,
    int* __restrict__ H, int* __restrict__ bb)
{
    __shared__ __align__(16) float sSf[32 * 140];
    unsigned short* sA = (unsigned short*)sSf;      // stride 136 bf16/row

    if (blockIdx.x == 0) {
        // per-bin exclusive scan over NPART partitions (row-contiguous), then
        // exclusive scan over bin totals -> absolute cursors in H, bases in bb
        __shared__ int sh[256];
        const int t = threadIdx.x;
        int run = 0;
        if (t < NBUCKET) {
            int base = t * NPART;
            for (int hb = 0; hb < NPART; hb++) {
                int v = H[base + hb];
                H[base + hb] = run;
                run += v;
            }
        }
        sh[t] = (t < NBUCKET) ? run : 0;
        int myrun = sh[t];
        __syncthreads();
        #pragma unroll
        for (int off = 1; off < 256; off <<= 1) {
            int u = (t >= off) ? sh[t - off] : 0;
            __syncthreads();
            sh[t] += u;
            __syncthreads();
        }
        int exc = sh[t] - myrun;
        if (t < NBUCKET) {
            bb[t] = exc;
            int base = t * NPART;
            for (int hb = 0; hb < NPART; hb++) H[base + hb] += exc;
        }
        if (t == 0) bb[NBUCKET] = E_N;
        return;
    }

    const int t = threadIdx.x;
    const int lane = t & 63;
    const int w = t >> 6;                            // == head
    const int nb = (blockIdx.x - 1) * 32;
    const int n15 = lane & 15;
    const int q = lane >> 4;
    const unsigned short* bfrag = (const unsigned short*)bfragw;

    #pragma unroll
    for (int i = 0; i < 4; i++) {
        int f = t + i * 256;
        int node = f >> 5;
        int kc = (f & 31) * 4;
        float4 v = {0.f, 0.f, 0.f, 0.f};
        if (nb + node < V_N)
            v = *(const float4*)(nf + (size_t)(nb + node) * NODE_IN + kc);
        uint2 u2 = make_uint2(pk2(v.x, v.y), pk2(v.z, v.w));
        *(uint2*)&sA[node * 136 + kc] = u2;
    }
    __syncthreads();

    f32x4 acc[2][4];
    #pragma unroll
    for (int m = 0; m < 2; m++)
        #pragma unroll
        for (int tt = 0; tt < 4; tt++) acc[m][tt] = (f32x4){0.f, 0.f, 0.f, 0.f};

    #pragma unroll
    for (int ks = 0; ks < 4; ks++) {
        bf16x8 a0 = *(const bf16x8*)&sA[n15 * 136 + ks * 32 + q * 8];
        bf16x8 a1 = *(const bf16x8*)&sA[(16 + n15) * 136 + ks * 32 + q * 8];
        #pragma unroll
        for (int tt = 0; tt < 4; tt++) {
            int nt = (tt < 2) ? (2 * w + tt) : (8 + 2 * w + (tt - 2));
            bf16x8 b = *(const bf16x8*)(bfrag + ((size_t)(nt * 4 + ks) * 64 + lane) * 8);
            acc[0][tt] = __builtin_amdgcn_mfma_f32_16x16x32_bf16(a0, b, acc[0][tt], 0, 0, 0);
            acc[1][tt] = __builtin_amdgcn_mfma_f32_16x16x32_bf16(a1, b, acc[1][tt], 0, 0, 0);
        }
    }

    // el/er for head w (all waves busy)
    {
        float al0 = attn_l[w * 32 + n15];
        float al1 = attn_l[w * 32 + 16 + n15];
        float ar0 = attn_r[w * 32 + n15];
        float ar1 = attn_r[w * 32 + 16 + n15];
        #pragma unroll
        for (int m = 0; m < 2; m++) {
            #pragma unroll
            for (int r = 0; r < 4; r++) {
                float fa = acc[m][0][r], fb = acc[m][1][r];
                float elp = fa * al0 + fb * al1;
                float erp = fa * ar0 + fb * ar1;
                elp += __shfl_xor(elp, 1); erp += __shfl_xor(erp, 1);
                elp += __shfl_xor(elp, 2); erp += __shfl_xor(erp, 2);
                elp += __shfl_xor(elp, 4); erp += __shfl_xor(erp, 4);
                elp += __shfl_xor(elp, 8); erp += __shfl_xor(erp, 8);
                int node = nb + m * 16 + q * 4 + r;
                if (n15 == 0 && node < V_N) {
                    el[node * 4 + w] = elp;
                    er[node * 4 + w] = erp;
                }
            }
        }
    }
    // ft f16 store, head-major: uint idx = node*64 + w*16 + n15
    #pragma unroll
    for (int m = 0; m < 2; m++)
        #pragma unroll
        for (int r = 0; r < 4; r++) {
            int node = nb + m * 16 + q * 4 + r;
            if (node < V_N)
                ftw[(size_t)node * 64 + w * 16 + n15] =
                    pkh2(acc[m][0][r], acc[m][1][r]);
        }
    __syncthreads();

    // residual: wave w stages cols 32w..32w+31 (tt=2,3)
    #pragma unroll
    for (int m = 0; m < 2; m++)
        #pragma unroll
        for (int tt = 2; tt < 4; tt++)
            #pragma unroll
            for (int r = 0; r < 4; r++)
                sSf[(m * 16 + q * 4 + r) * 140 + w * 32 + (tt - 2) * 16 + n15] =
                    acc[m][tt][r];
    __syncthreads();
    #pragma unroll
    for (int i = 0; i < 4; i++) {
        int u = t + i * 256;
        int node = u >> 5, c4 = (u & 31) * 4;
        if (nb + node < V_N) {
            float4 v = *(float4*)&sSf[node * 140 + c4];
            float4 b4 = *(const float4*)(bias + c4);
            v.x += b4.x; v.y += b4.y; v.z += b4.z; v.w += b4.w;
            *(float4*)(out + (size_t)(nb + node) * HF + c4) = v;
        }
    }
}

// K3: bin. Stream ef (coalesced quad-dot, verified), compute lee, place into
// bucket-grouped recb via LDS-atomic cursors (no global atomics).
// Block b owns edges [b*1024, b*1024+1024) and cursors H[bin][b].
__global__ __launch_bounds__(256) void k_bin(
    const float* __restrict__ ef, const int* __restrict__ src,
    const int* __restrict__ dst, const float* __restrict__ watt,
    const float* __restrict__ el, const int* __restrict__ H,
    uint4* __restrict__ recb)
{
    __shared__ float sw[64];
    __shared__ __align__(16) float see[256][4];
    __shared__ int boff[NBUCKET];
    const int t = threadIdx.x;
    const int b = blockIdx.x;
    if (t < 64) sw[t] = watt[t];
    for (int i = t; i < NBUCKET; i += 256) boff[i] = H[i * NPART + b];
    __syncthreads();
    const int lane = t & 63, w = t >> 6;
    const int k0 = (lane & 3) * 4;

    for (int c = 0; c < 4; c++) {
        const int base = b * 1024 + c * 256;
        // phase 1: quad (4 lanes) per edge; lane reads 16B of the 64B ef row
        #pragma unroll
        for (int r = 0; r < 4; r++) {
            int le = w * 64 + r * 16 + (lane >> 2);     // local edge 0..255
            int ge = base + le;
            float4 v = {0.f, 0.f, 0.f, 0.f};
            if (ge < E_N)
                v = *(const float4*)(ef + (size_t)ge * EDGE_IN + k0);
            float e0 = 0.f, e1 = 0.f, e2 = 0.f, e3 = 0.f;
            float vv[4] = {v.x, v.y, v.z, v.w};
            #pragma unroll
            for (int j = 0; j < 4; j++) {
                int k = k0 + j;
                e0 += vv[j] * sw[k * 4 + 0];
                e1 += vv[j] * sw[k * 4 + 1];
                e2 += vv[j] * sw[k * 4 + 2];
                e3 += vv[j] * sw[k * 4 + 3];
            }
            e0 += __shfl_xor(e0, 1); e1 += __shfl_xor(e1, 1);
            e2 += __shfl_xor(e2, 1); e3 += __shfl_xor(e3, 1);
            e0 += __shfl_xor(e0, 2); e1 += __shfl_xor(e1, 2);
            e2 += __shfl_xor(e2, 2); e3 += __shfl_xor(e3, 2);
            if ((lane & 3) == 0) {
                float4 o = {e0, e1, e2, e3};
                *(float4*)&see[le][0] = o;
            }
        }
        __syncthreads();

        // phase 2: 1 edge/thread, LDS cursor -> global slot
        int e = base + t;
        if (e < E_N) {
            int s = src[e], d = dst[e];
            int p = atomicAdd(&boff[d >> 8], 1);
            float4 ee = *(float4*)&see[t][0];
            float4 el4 = *(const float4*)(el + (size_t)s * 4);
            uint4 rr;
            rr.x = (unsigned)s;
            rr.y = pk2(el4.x + ee.x, el4.y + ee.y);
            rr.z = pk2(el4.z + ee.z, el4.w + ee.w);
            rr.w = (unsigned)d;
            recb[p] = rr;
        }
        __syncthreads();   // protect see reuse next chunk
    }
}

// K4: group. One block per bucket (256 dsts): LDS count + scan over the
// bucket's records (L2-hot), write rowp, permute records to dst-grouped rec.
__global__ __launch_bounds__(256) void k_group(
    const int* __restrict__ bb, const uint4* __restrict__ recb,
    uint4* __restrict__ rec, int* __restrict__ rowp)
{
    __shared__ int cnt[256];
    __shared__ int s1[256];
    __shared__ int cur[256];
    const int t = threadIdx.x;
    const int b = blockIdx.x;
    const int lo = bb[b], hi = bb[b + 1];

    cnt[t] = 0;
    __syncthreads();
    const int* recw = (const int*)recb;
    for (int i = lo + t; i < hi; i += 256)
        atomicAdd(&cnt[recw[4 * i + 3] & 255], 1);
    __syncthreads();
    int v = cnt[t];
    s1[t] = v;
    __syncthreads();
    #pragma unroll
    for (int off = 1; off < 256; off <<= 1) {
        int u = (t >= off) ? s1[t - off] : 0;
        __syncthreads();
        s1[t] += u;
        __syncthreads();
    }
    int exc = s1[t] - v;
    int d = (b << 8) + t;
    if (d < V_N) rowp[d] = lo + exc;
    if (b == 0 && t == 0) rowp[V_N] = E_N;
    cur[t] = lo + exc;
    __syncthreads();
    for (int i = lo + t; i < hi; i += 256) {
        uint4 r = recb[i];
        int dl = (int)(r.w & 255u);
        int p = atomicAdd(&cur[dl], 1);
        rec[p] = r;
    }
}

// K5: gather, 16-lane group per dst (avg deg = 16). 16 groups/block,
// 50000 = 3125*16 exactly. Each lane li owns 8 f16 output cols across ALL
// edges -> no cross-lane U reduction. s (denominator) reduced over 16 lanes.
__global__ __launch_bounds__(256) void k_gather(
    const int* __restrict__ row, const uint4* __restrict__ rec,
    const float* __restrict__ er,
    const unsigned* __restrict__ ftw, float* __restrict__ out)
{
    __shared__ unsigned aw[16][16][4];   // [group][edge][head] dup-half2 ex
    const int t = threadIdx.x;
    const int g = t >> 4;                // group in block
    const int li = t & 15;
    const int head = li >> 2;
    const int lanebase = t & 48;         // group base within the wave
    const int d = blockIdx.x * 16 + g;
    const int n0 = row[d];
    const int deg = row[d + 1] - n0;
    if (deg == 0) return;

    const float4 er4 = *(const float4*)(er + (size_t)d * 4);
    float4 s4 = {0.f, 0.f, 0.f, 0.f};
    __half2 ha0 = u2h(0u), ha1 = u2h(0u), ha2 = u2h(0u), ha3 = u2h(0u);
    __half2 hb0 = u2h(0u), hb1 = u2h(0u), hb2 = u2h(0u), hb3 = u2h(0u);

    for (int i0 = 0; i0 < deg; i0 += 16) {
        int chunk = min(16, deg - i0);
        int si = 0;
        float4 ex = {0.f, 0.f, 0.f, 0.f};
        if (li < chunk) {
            uint4 r = rec[n0 + i0 + li];
            si = (int)r.x;
            float x0 = bflo(r.y) + er4.x;
            float x1 = bfhi(r.y) + er4.y;
            float x2 = bflo(r.z) + er4.z;
            float x3 = bfhi(r.z) + er4.w;
            x0 = x0 >= 0.f ? x0 : NEG_SLOPE * x0;
            x1 = x1 >= 0.f ? x1 : NEG_SLOPE * x1;
            x2 = x2 >= 0.f ? x2 : NEG_SLOPE * x2;
            x3 = x3 >= 0.f ? x3 : NEG_SLOPE * x3;
            ex.x = __expf(x0); ex.y = __expf(x1);
            ex.z = __expf(x2); ex.w = __expf(x3);
            s4.x += ex.x; s4.y += ex.y; s4.z += ex.z; s4.w += ex.w;
        }
        uint4 ap;
        ap.x = pkh2(ex.x, ex.x); ap.y = pkh2(ex.y, ex.y);
        ap.z = pkh2(ex.z, ex.z); ap.w = pkh2(ex.w, ex.w);
        *(uint4*)&aw[g][li][0] = ap;
        asm volatile("s_waitcnt lgkmcnt(0)" ::: "memory");

        int ce = (chunk + 1) & ~1;       // odd tail edge has ex=0,si=0 -> safe
        for (int j = 0; j < ce; j += 2) {
            int s0 = __shfl(si, lanebase + j);
            int s1v = __shfl(si, lanebase + j + 1);
            unsigned a0 = aw[g][j][head];
            unsigned a1 = aw[g][j + 1][head];
            uint4 w0 = *(const uint4*)(ftw + (size_t)s0 * 64 + li * 4);
            uint4 w1 = *(const uint4*)(ftw + (size_t)s1v * 64 + li * 4);
            ha0 = __hfma2(u2h(w0.x), u2h(a0), ha0);
            ha1 = __hfma2(u2h(w0.y), u2h(a0), ha1);
            ha2 = __hfma2(u2h(w0.z), u2h(a0), ha2);
            ha3 = __hfma2(u2h(w0.w), u2h(a0), ha3);
            hb0 = __hfma2(u2h(w1.x), u2h(a1), hb0);
            hb1 = __hfma2(u2h(w1.y), u2h(a1), hb1);
            hb2 = __hfma2(u2h(w1.z), u2h(a1), hb2);
            hb3 = __hfma2(u2h(w1.w), u2h(a1), hb3);
        }
    }
    // denominator: reduce s4 over the 16-lane group
    #pragma unroll
    for (int off = 1; off < 16; off <<= 1) {
        s4.x += __shfl_xor(s4.x, off);
        s4.y += __shfl_xor(s4.y, off);
        s4.z += __shfl_xor(s4.z, off);
        s4.w += __shfl_xor(s4.w, off);
    }
    ha0 = __hadd2(ha0, hb0); ha1 = __hadd2(ha1, hb1);
    ha2 = __hadd2(ha2, hb2); ha3 = __hadd2(ha3, hb3);

    float rsv = 1.f / (head == 0 ? s4.x : head == 1 ? s4.y :
                       head == 2 ? s4.z : s4.w);
    // lane li: cols head*32 + (li&3)*4 + {0..3} and +16
    float* op = out + (size_t)d * HF + head * 32 + (li & 3) * 4;
    float4 r0 = *(float4*)op;
    r0.x += __low2float(ha0) * rsv; r0.y += __low2float(ha1) * rsv;
    r0.z += __low2float(ha2) * rsv; r0.w += __low2float(ha3) * rsv;
    *(float4*)op = r0;
    float4 r1 = *(float4*)(op + 16);
    r1.x += __high2float(ha0) * rsv; r1.y += __high2float(ha1) * rsv;
    r1.z += __high2float(ha2) * rsv; r1.w += __high2float(ha3) * rsv;
    *(float4*)(op + 16) = r1;
}

extern "C" void kernel_launch(void* const* d_in, const int* in_sizes, int n_in,
                              void* d_out, int out_size, void* d_ws, size_t ws_size,
                              hipStream_t stream) {
    const float* nf     = (const float*)d_in[0];
    const float* ef     = (const float*)d_in[1];
    const int*   src    = (const int*)d_in[2];
    const int*   dst    = (const int*)d_in[3];
    const float* Wn     = (const float*)d_in[4];
    const float* We     = (const float*)d_in[5];
    const float* attn_l = (const float*)d_in[6];
    const float* attn_r = (const float*)d_in[7];
    const float* attn_e = (const float*)d_in[8];
    const float* Wr     = (const float*)d_in[9];
    const float* bias   = (const float*)d_in[10];
    float* out = (float*)d_out;

    unsigned* wsw  = (unsigned*)d_ws;
    unsigned* ftw  = wsw + OFF_FT;
    float* el      = (float*)(wsw + OFF_EL);
    float* er      = (float*)(wsw + OFF_ER);
    int* rowp      = (int*)(wsw + OFF_ROW);
    int* H         = (int*)(wsw + OFF_H);
    int* bb        = (int*)(wsw + OFF_BB);
    float* watt    = (float*)(wsw + OFF_WATT);
    unsigned* bfrag = wsw + OFF_BFRAG;
    uint4* recb    = (uint4*)(wsw + OFF_RECB);
    uint4* rec     = (uint4*)(wsw + OFF_REC);

    k_prephist<<<PREP_BLKS + NPART, 256, 0, stream>>>(
        We, attn_e, Wn, Wr, dst, watt, bfrag, H);
    k_nodescan<<<1 + NODE_BLKS, 256, 0, stream>>>(
        nf, bfrag, attn_l, attn_r, bias, ftw, el, er, out, H, bb);
    k_bin<<<NPART, 256, 0, stream>>>(ef, src, dst, watt, el, H, recb);
    k_group<<<NBUCKET, 256, 0, stream>>>(bb, recb, rec, rowp);
    k_gather<<<V_N / 16, 256, 0, stream>>>(rowp, rec, er, ftw, out);
}

// Round 9
// 225.032 us; speedup vs baseline: 1.3362x; 1.3362x over previous
//
#include <hip/hip_runtime.h>
#include <hip/hip_fp16.h>
#include <cstdint>

#define V_N 50000
#define E_N 800000
#define NODE_IN 128
#define EDGE_IN 16
#define HF 128
#define NEG_SLOPE 0.2f
#define NBUCKET 196     // ceil(50000/256) coarse dst buckets (dst>>8)
#define NPART 784       // edge partitions of 1024 for hist/bin
#define CAP 8192        // fixed recb capacity per bucket (expected 4096)
#define NODE_BLKS 1563  // ceil(50000/32)
#define PREP_BLKS 64

// ---- workspace layout (4-byte word offsets) ----
#define OFF_FT    0         // V*64 words (f16 ft, head-major)
#define OFF_EL    3200000   // V*4
#define OFF_ER    3400000   // V*4
#define OFF_ROW   3600000   // V+1 ints (+pad)
#define OFF_H     3650260   // NBUCKET*NPART ints = 153664 (H[bin][part])
#define OFF_BSUM  3803924   // NBUCKET ints (+pad)
#define OFF_WATT  3804180   // 64
#define OFF_BFRAG 3804244   // 16384 words (16B-aligned)
#define OFF_RECB  3820628   // NBUCKET*CAP*4 words = 6422528 (16B-aligned)
#define OFF_REC   10243156  // E*4 words (dst-grouped records, 16B-aligned)
// total ~13.44M words = 53.8 MB

typedef short bf16x8 __attribute__((ext_vector_type(8)));
typedef float f32x4 __attribute__((ext_vector_type(4)));

__device__ __forceinline__ unsigned short f2bf(float f) {
    unsigned u = __float_as_uint(f);
    u += 0x7fffu + ((u >> 16) & 1u);   // round-to-nearest-even
    return (unsigned short)(u >> 16);
}
__device__ __forceinline__ unsigned pk2(float lo, float hi) {
    return (unsigned)f2bf(lo) | ((unsigned)f2bf(hi) << 16);
}
__device__ __forceinline__ float bflo(unsigned w) { return __uint_as_float(w << 16); }
__device__ __forceinline__ float bfhi(unsigned w) { return __uint_as_float(w & 0xffff0000u); }

typedef __fp16 fp16x2 __attribute__((ext_vector_type(2)));
__device__ __forceinline__ unsigned pkh2(float a, float b) {
    fp16x2 h = __builtin_amdgcn_cvt_pkrtz(a, b);   // v_cvt_pkrtz_f16_f32
    return __builtin_bit_cast(unsigned, h);
}
__device__ __forceinline__ __half2 u2h(unsigned u) {
    return __builtin_bit_cast(__half2, u);
}
__device__ __forceinline__ unsigned h2u(__half2 h) {
    return __builtin_bit_cast(unsigned, h);
}

// K1: prep (blocks < PREP_BLKS: watt + bfrag) ∥ bucket-hist (LDS, no global
// atomics): partition hb covers edges [hb*1024, hb*1024+1024).
__global__ __launch_bounds__(256) void k_prephist(
    const float* __restrict__ We, const float* __restrict__ attn_e,
    const float* __restrict__ Wn, const float* __restrict__ Wr,
    const int* __restrict__ dst,
    float* __restrict__ watt, unsigned* __restrict__ bfrag,
    int* __restrict__ H)
{
    const int t = threadIdx.x;
    if (blockIdx.x >= PREP_BLKS) {
        int hb = blockIdx.x - PREP_BLKS;
        __shared__ int h[NBUCKET];
        for (int i = t; i < NBUCKET; i += 256) h[i] = 0;
        __syncthreads();
        #pragma unroll
        for (int c = 0; c < 4; c++) {
            int e = hb * 1024 + c * 256 + t;
            if (e < E_N) atomicAdd(&h[dst[e] >> 8], 1);
        }
        __syncthreads();
        for (int i = t; i < NBUCKET; i += 256) H[i * NPART + hb] = h[i];
        return;
    }
    int g = blockIdx.x * 256 + t;
    if (blockIdx.x == 0 && t < 64) {
        int k = t >> 2, hh = t & 3;
        float s = 0.f;
        #pragma unroll
        for (int f = 0; f < 32; f++)
            s += We[k * HF + hh * 32 + f] * attn_e[hh * 32 + f];
        watt[k * 4 + hh] = s;
    }
    // g < 16384 always (64 blocks x 256)
    {
        int c    = g >> 8;
        int lane = (g >> 2) & 63;
        int jp   = g & 3;
        int nt = c >> 2, ks = c & 3;
        int col = nt * 16 + (lane & 15);
        int k   = ks * 32 + (lane >> 4) * 8 + jp * 2;
        const float* W = (col < 128) ? Wn : Wr;
        int cc = col & 127;
        float x0 = W[(size_t)k * 128 + cc];
        float x1 = W[(size_t)(k + 1) * 128 + cc];
        bfrag[g] = pk2(x0, x1);
    }
}

// K2: blocks [0,NBUCKET) = per-bin cursor scan (PARALLEL, one bin/block:
// contiguous 784-int row, int4 loads, LDS scan; cursors absolute via
// bin*CAP base -> no cross-bin dependency) ∥ node MFMA.
__global__ __launch_bounds__(256) void k_nodescan(
    const float* __restrict__ nf, const unsigned* __restrict__ bfragw,
    const float* __restrict__ attn_l, const float* __restrict__ attn_r,
    const float* __restrict__ bias,
    unsigned* __restrict__ ftw, float* __restrict__ el,
    float* __restrict__ er, float* __restrict__ out,
    int* __restrict__ H, int* __restrict__ binsum)
{
    __shared__ __align__(16) float sSf[32 * 140];
    unsigned short* sA = (unsigned short*)sSf;      // stride 136 bf16/row

    if (blockIdx.x < NBUCKET) {
        int* shi = (int*)sSf;
        const int bin = blockIdx.x;
        const int t = threadIdx.x;
        const int base = bin * NPART;
        int4 v = {0, 0, 0, 0};
        if (t < NPART / 4) v = *(const int4*)&H[base + t * 4];
        int ls = v.x + v.y + v.z + v.w;
        shi[t] = ls;
        __syncthreads();
        #pragma unroll
        for (int off = 1; off < 256; off <<= 1) {
            int u = (t >= off) ? shi[t - off] : 0;
            __syncthreads();
            shi[t] += u;
            __syncthreads();
        }
        int exc = shi[t] - ls;
        if (t < NPART / 4) {
            int c0 = bin * CAP + exc;
            int4 o;
            o.x = c0;
            o.y = c0 + v.x;
            o.z = c0 + v.x + v.y;
            o.w = c0 + v.x + v.y + v.z;
            *(int4*)&H[base + t * 4] = o;
        }
        if (t == 255) binsum[bin] = shi[255];
        return;
    }

    const int t = threadIdx.x;
    const int lane = t & 63;
    const int w = t >> 6;                            // == head
    const int nb = (blockIdx.x - NBUCKET) * 32;
    const int n15 = lane & 15;
    const int q = lane >> 4;
    const unsigned short* bfrag = (const unsigned short*)bfragw;

    #pragma unroll
    for (int i = 0; i < 4; i++) {
        int f = t + i * 256;
        int node = f >> 5;
        int kc = (f & 31) * 4;
        float4 v = {0.f, 0.f, 0.f, 0.f};
        if (nb + node < V_N)
            v = *(const float4*)(nf + (size_t)(nb + node) * NODE_IN + kc);
        uint2 u2 = make_uint2(pk2(v.x, v.y), pk2(v.z, v.w));
        *(uint2*)&sA[node * 136 + kc] = u2;
    }
    __syncthreads();

    f32x4 acc[2][4];
    #pragma unroll
    for (int m = 0; m < 2; m++)
        #pragma unroll
        for (int tt = 0; tt < 4; tt++) acc[m][tt] = (f32x4){0.f, 0.f, 0.f, 0.f};

    #pragma unroll
    for (int ks = 0; ks < 4; ks++) {
        bf16x8 a0 = *(const bf16x8*)&sA[n15 * 136 + ks * 32 + q * 8];
        bf16x8 a1 = *(const bf16x8*)&sA[(16 + n15) * 136 + ks * 32 + q * 8];
        #pragma unroll
        for (int tt = 0; tt < 4; tt++) {
            int nt = (tt < 2) ? (2 * w + tt) : (8 + 2 * w + (tt - 2));
            bf16x8 b = *(const bf16x8*)(bfrag + ((size_t)(nt * 4 + ks) * 64 + lane) * 8);
            acc[0][tt] = __builtin_amdgcn_mfma_f32_16x16x32_bf16(a0, b, acc[0][tt], 0, 0, 0);
            acc[1][tt] = __builtin_amdgcn_mfma_f32_16x16x32_bf16(a1, b, acc[1][tt], 0, 0, 0);
        }
    }

    // el/er for head w (all waves busy)
    {
        float al0 = attn_l[w * 32 + n15];
        float al1 = attn_l[w * 32 + 16 + n15];
        float ar0 = attn_r[w * 32 + n15];
        float ar1 = attn_r[w * 32 + 16 + n15];
        #pragma unroll
        for (int m = 0; m < 2; m++) {
            #pragma unroll
            for (int r = 0; r < 4; r++) {
                float fa = acc[m][0][r], fb = acc[m][1][r];
                float elp = fa * al0 + fb * al1;
                float erp = fa * ar0 + fb * ar1;
                elp += __shfl_xor(elp, 1); erp += __shfl_xor(erp, 1);
                elp += __shfl_xor(elp, 2); erp += __shfl_xor(erp, 2);
                elp += __shfl_xor(elp, 4); erp += __shfl_xor(erp, 4);
                elp += __shfl_xor(elp, 8); erp += __shfl_xor(erp, 8);
                int node = nb + m * 16 + q * 4 + r;
                if (n15 == 0 && node < V_N) {
                    el[node * 4 + w] = elp;
                    er[node * 4 + w] = erp;
                }
            }
        }
    }
    // ft f16 store, head-major: uint idx = node*64 + w*16 + n15
    #pragma unroll
    for (int m = 0; m < 2; m++)
        #pragma unroll
        for (int r = 0; r < 4; r++) {
            int node = nb + m * 16 + q * 4 + r;
            if (node < V_N)
                ftw[(size_t)node * 64 + w * 16 + n15] =
                    pkh2(acc[m][0][r], acc[m][1][r]);
        }
    __syncthreads();

    // residual: wave w stages cols 32w..32w+31 (tt=2,3)
    #pragma unroll
    for (int m = 0; m < 2; m++)
        #pragma unroll
        for (int tt = 2; tt < 4; tt++)
            #pragma unroll
            for (int r = 0; r < 4; r++)
                sSf[(m * 16 + q * 4 + r) * 140 + w * 32 + (tt - 2) * 16 + n15] =
                    acc[m][tt][r];
    __syncthreads();
    #pragma unroll
    for (int i = 0; i < 4; i++) {
        int u = t + i * 256;
        int node = u >> 5, c4 = (u & 31) * 4;
        if (nb + node < V_N) {
            float4 v = *(float4*)&sSf[node * 140 + c4];
            float4 b4 = *(const float4*)(bias + c4);
            v.x += b4.x; v.y += b4.y; v.z += b4.z; v.w += b4.w;
            *(float4*)(out + (size_t)(nb + node) * HF + c4) = v;
        }
    }
}

// K3: bin. Stream ef (coalesced quad-dot, verified), compute lee, place into
// bucket-grouped recb via LDS-atomic cursors (no global atomics).
// Block b owns edges [b*1024, b*1024+1024) and cursors H[bin][b] (absolute).
__global__ __launch_bounds__(256) void k_bin(
    const float* __restrict__ ef, const int* __restrict__ src,
    const int* __restrict__ dst, const float* __restrict__ watt,
    const float* __restrict__ el, const int* __restrict__ H,
    uint4* __restrict__ recb)
{
    __shared__ float sw[64];
    __shared__ __align__(16) float see[256][4];
    __shared__ int boff[NBUCKET];
    const int t = threadIdx.x;
    const int b = blockIdx.x;
    if (t < 64) sw[t] = watt[t];
    for (int i = t; i < NBUCKET; i += 256) boff[i] = H[i * NPART + b];
    __syncthreads();
    const int lane = t & 63, w = t >> 6;
    const int k0 = (lane & 3) * 4;

    for (int c = 0; c < 4; c++) {
        const int base = b * 1024 + c * 256;
        // phase 1: quad (4 lanes) per edge; lane reads 16B of the 64B ef row
        #pragma unroll
        for (int r = 0; r < 4; r++) {
            int le = w * 64 + r * 16 + (lane >> 2);     // local edge 0..255
            int ge = base + le;
            float4 v = {0.f, 0.f, 0.f, 0.f};
            if (ge < E_N)
                v = *(const float4*)(ef + (size_t)ge * EDGE_IN + k0);
            float e0 = 0.f, e1 = 0.f, e2 = 0.f, e3 = 0.f;
            float vv[4] = {v.x, v.y, v.z, v.w};
            #pragma unroll
            for (int j = 0; j < 4; j++) {
                int k = k0 + j;
                e0 += vv[j] * sw[k * 4 + 0];
                e1 += vv[j] * sw[k * 4 + 1];
                e2 += vv[j] * sw[k * 4 + 2];
                e3 += vv[j] * sw[k * 4 + 3];
            }
            e0 += __shfl_xor(e0, 1); e1 += __shfl_xor(e1, 1);
            e2 += __shfl_xor(e2, 1); e3 += __shfl_xor(e3, 1);
            e0 += __shfl_xor(e0, 2); e1 += __shfl_xor(e1, 2);
            e2 += __shfl_xor(e2, 2); e3 += __shfl_xor(e3, 2);
            if ((lane & 3) == 0) {
                float4 o = {e0, e1, e2, e3};
                *(float4*)&see[le][0] = o;
            }
        }
        __syncthreads();

        // phase 2: 1 edge/thread, LDS cursor -> global slot
        int e = base + t;
        if (e < E_N) {
            int s = src[e], d = dst[e];
            int p = atomicAdd(&boff[d >> 8], 1);
            float4 ee = *(float4*)&see[t][0];
            float4 el4 = *(const float4*)(el + (size_t)s * 4);
            uint4 rr;
            rr.x = (unsigned)s;
            rr.y = pk2(el4.x + ee.x, el4.y + ee.y);
            rr.z = pk2(el4.z + ee.z, el4.w + ee.w);
            rr.w = (unsigned)d;
            recb[p] = rr;
        }
        __syncthreads();   // protect see reuse next chunk
    }
}

// K4: group. One block per bucket (256 dsts): global base from binsum prefix
// (redundant per-block, <=196 L2-hot ints), LDS count + scan over the
// bucket's records, write rowp, permute records to compact dst-grouped rec.
__global__ __launch_bounds__(256) void k_group(
    const int* __restrict__ binsum, const uint4* __restrict__ recb,
    uint4* __restrict__ rec, int* __restrict__ rowp)
{
    __shared__ int cnt[256];
    __shared__ int s1[256];
    __shared__ int cur[256];
    const int t = threadIdx.x;
    const int b = blockIdx.x;

    // global base = sum binsum[0..b)
    int pre = 0;
    for (int i = t; i < b; i += 256) pre += binsum[i];
    s1[t] = pre;
    __syncthreads();
    #pragma unroll
    for (int off = 128; off > 0; off >>= 1) {
        if (t < off) s1[t] += s1[t + off];
        __syncthreads();
    }
    const int gbase = s1[0];
    const int size = binsum[b];
    const int src0 = b * CAP;
    __syncthreads();

    cnt[t] = 0;
    __syncthreads();
    const int* recw = (const int*)recb;
    for (int i = t; i < size; i += 256)
        atomicAdd(&cnt[recw[4 * (src0 + i) + 3] & 255], 1);
    __syncthreads();
    int v = cnt[t];
    s1[t] = v;
    __syncthreads();
    #pragma unroll
    for (int off = 1; off < 256; off <<= 1) {
        int u = (t >= off) ? s1[t - off] : 0;
        __syncthreads();
        s1[t] += u;
        __syncthreads();
    }
    int exc = s1[t] - v;
    int d = (b << 8) + t;
    if (d < V_N) rowp[d] = gbase + exc;
    if (b == 0 && t == 0) rowp[V_N] = E_N;
    cur[t] = gbase + exc;
    __syncthreads();
    for (int i = t; i < size; i += 256) {
        uint4 r = recb[src0 + i];
        int dl = (int)(r.w & 255u);
        int p = atomicAdd(&cur[dl], 1);
        rec[p] = r;
    }
}

// K5: gather, 16-lane group per dst (avg deg = 16). 16 groups/block,
// 50000 = 3125*16 exactly. Each lane li owns 8 f16 output cols across ALL
// edges -> no cross-lane U reduction. s (denominator) reduced over 16 lanes.
__global__ __launch_bounds__(256) void k_gather(
    const int* __restrict__ row, const uint4* __restrict__ rec,
    const float* __restrict__ er,
    const unsigned* __restrict__ ftw, float* __restrict__ out)
{
    __shared__ unsigned aw[16][16][4];   // [group][edge][head] dup-half2 ex
    const int t = threadIdx.x;
    const int g = t >> 4;                // group in block
    const int li = t & 15;
    const int head = li >> 2;
    const int lanebase = t & 48;         // group base within the wave
    const int d = blockIdx.x * 16 + g;
    const int n0 = row[d];
    const int deg = row[d + 1] - n0;
    if (deg == 0) return;

    const float4 er4 = *(const float4*)(er + (size_t)d * 4);
    float4 s4 = {0.f, 0.f, 0.f, 0.f};
    __half2 ha0 = u2h(0u), ha1 = u2h(0u), ha2 = u2h(0u), ha3 = u2h(0u);
    __half2 hb0 = u2h(0u), hb1 = u2h(0u), hb2 = u2h(0u), hb3 = u2h(0u);

    for (int i0 = 0; i0 < deg; i0 += 16) {
        int chunk = min(16, deg - i0);
        int si = 0;
        float4 ex = {0.f, 0.f, 0.f, 0.f};
        if (li < chunk) {
            uint4 r = rec[n0 + i0 + li];
            si = (int)r.x;
            float x0 = bflo(r.y) + er4.x;
            float x1 = bfhi(r.y) + er4.y;
            float x2 = bflo(r.z) + er4.z;
            float x3 = bfhi(r.z) + er4.w;
            x0 = x0 >= 0.f ? x0 : NEG_SLOPE * x0;
            x1 = x1 >= 0.f ? x1 : NEG_SLOPE * x1;
            x2 = x2 >= 0.f ? x2 : NEG_SLOPE * x2;
            x3 = x3 >= 0.f ? x3 : NEG_SLOPE * x3;
            ex.x = __expf(x0); ex.y = __expf(x1);
            ex.z = __expf(x2); ex.w = __expf(x3);
            s4.x += ex.x; s4.y += ex.y; s4.z += ex.z; s4.w += ex.w;
        }
        uint4 ap;
        ap.x = pkh2(ex.x, ex.x); ap.y = pkh2(ex.y, ex.y);
        ap.z = pkh2(ex.z, ex.z); ap.w = pkh2(ex.w, ex.w);
        *(uint4*)&aw[g][li][0] = ap;
        asm volatile("s_waitcnt lgkmcnt(0)" ::: "memory");

        int ce = (chunk + 1) & ~1;       // odd tail edge has ex=0,si=0 -> safe
        for (int j = 0; j < ce; j += 2) {
            int s0 = __shfl(si, lanebase + j);
            int s1v = __shfl(si, lanebase + j + 1);
            unsigned a0 = aw[g][j][head];
            unsigned a1 = aw[g][j + 1][head];
            uint4 w0 = *(const uint4*)(ftw + (size_t)s0 * 64 + li * 4);
            uint4 w1 = *(const uint4*)(ftw + (size_t)s1v * 64 + li * 4);
            ha0 = __hfma2(u2h(w0.x), u2h(a0), ha0);
            ha1 = __hfma2(u2h(w0.y), u2h(a0), ha1);
            ha2 = __hfma2(u2h(w0.z), u2h(a0), ha2);
            ha3 = __hfma2(u2h(w0.w), u2h(a0), ha3);
            hb0 = __hfma2(u2h(w1.x), u2h(a1), hb0);
            hb1 = __hfma2(u2h(w1.y), u2h(a1), hb1);
            hb2 = __hfma2(u2h(w1.z), u2h(a1), hb2);
            hb3 = __hfma2(u2h(w1.w), u2h(a1), hb3);
        }
    }
    // denominator: reduce s4 over the 16-lane group
    #pragma unroll
    for (int off = 1; off < 16; off <<= 1) {
        s4.x += __shfl_xor(s4.x, off);
        s4.y += __shfl_xor(s4.y, off);
        s4.z += __shfl_xor(s4.z, off);
        s4.w += __shfl_xor(s4.w, off);
    }
    ha0 = __hadd2(ha0, hb0); ha1 = __hadd2(ha1, hb1);
    ha2 = __hadd2(ha2, hb2); ha3 = __hadd2(ha3, hb3);

    float rsv = 1.f / (head == 0 ? s4.x : head == 1 ? s4.y :
                       head == 2 ? s4.z : s4.w);
    // lane li: cols head*32 + (li&3)*4 + {0..3} and +16
    float* op = out + (size_t)d * HF + head * 32 + (li & 3) * 4;
    float4 r0 = *(float4*)op;
    r0.x += __low2float(ha0) * rsv; r0.y += __low2float(ha1) * rsv;
    r0.z += __low2float(ha2) * rsv; r0.w += __low2float(ha3) * rsv;
    *(float4*)op = r0;
    float4 r1 = *(float4*)(op + 16);
    r1.x += __high2float(ha0) * rsv; r1.y += __high2float(ha1) * rsv;
    r1.z += __high2float(ha2) * rsv; r1.w += __high2float(ha3) * rsv;
    *(float4*)(op + 16) = r1;
}

extern "C" void kernel_launch(void* const* d_in, const int* in_sizes, int n_in,
                              void* d_out, int out_size, void* d_ws, size_t ws_size,
                              hipStream_t stream) {
    const float* nf     = (const float*)d_in[0];
    const float* ef     = (const float*)d_in[1];
    const int*   src    = (const int*)d_in[2];
    const int*   dst    = (const int*)d_in[3];
    const float* Wn     = (const float*)d_in[4];
    const float* We     = (const float*)d_in[5];
    const float* attn_l = (const float*)d_in[6];
    const float* attn_r = (const float*)d_in[7];
    const float* attn_e = (const float*)d_in[8];
    const float* Wr     = (const float*)d_in[9];
    const float* bias   = (const float*)d_in[10];
    float* out = (float*)d_out;

    unsigned* wsw  = (unsigned*)d_ws;
    unsigned* ftw  = wsw + OFF_FT;
    float* el      = (float*)(wsw + OFF_EL);
    float* er      = (float*)(wsw + OFF_ER);
    int* rowp      = (int*)(wsw + OFF_ROW);
    int* H         = (int*)(wsw + OFF_H);
    int* binsum    = (int*)(wsw + OFF_BSUM);
    float* watt    = (float*)(wsw + OFF_WATT);
    unsigned* bfrag = wsw + OFF_BFRAG;
    uint4* recb    = (uint4*)(wsw + OFF_RECB);
    uint4* rec     = (uint4*)(wsw + OFF_REC);

    k_prephist<<<PREP_BLKS + NPART, 256, 0, stream>>>(
        We, attn_e, Wn, Wr, dst, watt, bfrag, H);
    k_nodescan<<<NBUCKET + NODE_BLKS, 256, 0, stream>>>(
        nf, bfrag, attn_l, attn_r, bias, ftw, el, er, out, H, binsum);
    k_bin<<<NPART, 256, 0, stream>>>(ef, src, dst, watt, el, H, recb);
    k_group<<<NBUCKET, 256, 0, stream>>>(binsum, recb, rec, rowp);
    k_gather<<<V_N / 16, 256, 0, stream>>>(rowp, rec, er, ftw, out);
}

// Round 10
// 218.393 us; speedup vs baseline: 1.3768x; 1.0304x over previous
//
#include <hip/hip_runtime.h>
#include <hip/hip_fp16.h>
#include <cstdint>

#define V_N 50000
#define E_N 800000
#define NODE_IN 128
#define EDGE_IN 16
#define HF 128
#define NEG_SLOPE 0.2f
#define NBUCKET 196     // ceil(50000/256) coarse dst buckets (dst>>8)
#define NPART 1563      // edge partitions of 512 (last partial: 256)
#define PSZ 512
#define CAP 8192        // fixed recb capacity per bucket (expected 4096)
#define NODE_BLKS 1563  // ceil(50000/32)
#define PREP_BLKS 64

// ---- workspace layout (4-byte word offsets) ----
#define OFF_FT    0         // V*64 words (f16 ft, head-major)
#define OFF_EL    3200000   // V*4
#define OFF_ER    3400000   // V*4
#define OFF_ROW   3600000   // V+1 ints (+pad)
#define OFF_H     3650260   // NPART*NBUCKET ints = 306348 (H[part][bin])
#define OFF_BSUM  3956608   // NBUCKET ints (+pad)
#define OFF_WATT  3956864   // 64
#define OFF_BFRAG 3956928   // 16384 words (16B-aligned)
#define OFF_RECB  3973312   // NBUCKET*CAP*4 words = 6422528 (16B-aligned)
#define OFF_REC   10395840  // E*4 words (dst-grouped records, 16B-aligned)
// total ~13.6M words = 54.4 MB

typedef short bf16x8 __attribute__((ext_vector_type(8)));
typedef float f32x4 __attribute__((ext_vector_type(4)));

__device__ __forceinline__ unsigned short f2bf(float f) {
    unsigned u = __float_as_uint(f);
    u += 0x7fffu + ((u >> 16) & 1u);   // round-to-nearest-even
    return (unsigned short)(u >> 16);
}
__device__ __forceinline__ unsigned pk2(float lo, float hi) {
    return (unsigned)f2bf(lo) | ((unsigned)f2bf(hi) << 16);
}
__device__ __forceinline__ float bflo(unsigned w) { return __uint_as_float(w << 16); }
__device__ __forceinline__ float bfhi(unsigned w) { return __uint_as_float(w & 0xffff0000u); }

typedef __fp16 fp16x2 __attribute__((ext_vector_type(2)));
__device__ __forceinline__ unsigned pkh2(float a, float b) {
    fp16x2 h = __builtin_amdgcn_cvt_pkrtz(a, b);   // v_cvt_pkrtz_f16_f32
    return __builtin_bit_cast(unsigned, h);
}
__device__ __forceinline__ __half2 u2h(unsigned u) {
    return __builtin_bit_cast(__half2, u);
}
__device__ __forceinline__ unsigned h2u(__half2 h) {
    return __builtin_bit_cast(unsigned, h);
}

// K1: prep (blocks < PREP_BLKS: watt + bfrag) ∥ bucket-hist (LDS, no global
// atomics): partition hb covers edges [hb*512, hb*512+512).
// H row-major by partition: H[hb*NBUCKET + bin] -> contiguous row write.
__global__ __launch_bounds__(256) void k_prephist(
    const float* __restrict__ We, const float* __restrict__ attn_e,
    const float* __restrict__ Wn, const float* __restrict__ Wr,
    const int* __restrict__ dst,
    float* __restrict__ watt, unsigned* __restrict__ bfrag,
    int* __restrict__ H)
{
    const int t = threadIdx.x;
    if (blockIdx.x >= PREP_BLKS) {
        int hb = blockIdx.x - PREP_BLKS;
        __shared__ int h[NBUCKET];
        for (int i = t; i < NBUCKET; i += 256) h[i] = 0;
        __syncthreads();
        #pragma unroll
        for (int c = 0; c < 2; c++) {
            int e = hb * PSZ + c * 256 + t;
            if (e < E_N) atomicAdd(&h[dst[e] >> 8], 1);
        }
        __syncthreads();
        for (int i = t; i < NBUCKET; i += 256) H[hb * NBUCKET + i] = h[i];
        return;
    }
    int g = blockIdx.x * 256 + t;
    if (blockIdx.x == 0 && t < 64) {
        int k = t >> 2, hh = t & 3;
        float s = 0.f;
        #pragma unroll
        for (int f = 0; f < 32; f++)
            s += We[k * HF + hh * 32 + f] * attn_e[hh * 32 + f];
        watt[k * 4 + hh] = s;
    }
    // g < 16384 always (64 blocks x 256)
    {
        int c    = g >> 8;
        int lane = (g >> 2) & 63;
        int jp   = g & 3;
        int nt = c >> 2, ks = c & 3;
        int col = nt * 16 + (lane & 15);
        int k   = ks * 32 + (lane >> 4) * 8 + jp * 2;
        const float* W = (col < 128) ? Wn : Wr;
        int cc = col & 127;
        float x0 = W[(size_t)k * 128 + cc];
        float x1 = W[(size_t)(k + 1) * 128 + cc];
        bfrag[g] = pk2(x0, x1);
    }
}

// K2: blocks [0,NBUCKET) = per-bin cursor scan (one bin/block: column walk
// over NPART partitions, 8/thread; absolute cursors via bin*CAP base -> no
// cross-bin dependency; scattered reads hidden under node MFMA) ∥ node MFMA.
__global__ __launch_bounds__(256) void k_nodescan(
    const float* __restrict__ nf, const unsigned* __restrict__ bfragw,
    const float* __restrict__ attn_l, const float* __restrict__ attn_r,
    const float* __restrict__ bias,
    unsigned* __restrict__ ftw, float* __restrict__ el,
    float* __restrict__ er, float* __restrict__ out,
    int* __restrict__ H, int* __restrict__ binsum)
{
    __shared__ __align__(16) float sSf[32 * 140];
    unsigned short* sA = (unsigned short*)sSf;      // stride 136 bf16/row

    if (blockIdx.x < NBUCKET) {
        int* shi = (int*)sSf;
        const int bin = blockIdx.x;
        const int t = threadIdx.x;
        int v[8];
        int ls = 0;
        #pragma unroll
        for (int j = 0; j < 8; j++) {
            int p = t * 8 + j;
            v[j] = (p < NPART) ? H[p * NBUCKET + bin] : 0;
            ls += v[j];
        }
        shi[t] = ls;
        __syncthreads();
        #pragma unroll
        for (int off = 1; off < 256; off <<= 1) {
            int u = (t >= off) ? shi[t - off] : 0;
            __syncthreads();
            shi[t] += u;
            __syncthreads();
        }
        int c = bin * CAP + shi[t] - ls;
        #pragma unroll
        for (int j = 0; j < 8; j++) {
            int p = t * 8 + j;
            if (p < NPART) { H[p * NBUCKET + bin] = c; c += v[j]; }
        }
        if (t == 255) binsum[bin] = shi[255];
        return;
    }

    const int t = threadIdx.x;
    const int lane = t & 63;
    const int w = t >> 6;                            // == head
    const int nb = (blockIdx.x - NBUCKET) * 32;
    const int n15 = lane & 15;
    const int q = lane >> 4;
    const unsigned short* bfrag = (const unsigned short*)bfragw;

    #pragma unroll
    for (int i = 0; i < 4; i++) {
        int f = t + i * 256;
        int node = f >> 5;
        int kc = (f & 31) * 4;
        float4 v = {0.f, 0.f, 0.f, 0.f};
        if (nb + node < V_N)
            v = *(const float4*)(nf + (size_t)(nb + node) * NODE_IN + kc);
        uint2 u2 = make_uint2(pk2(v.x, v.y), pk2(v.z, v.w));
        *(uint2*)&sA[node * 136 + kc] = u2;
    }
    __syncthreads();

    f32x4 acc[2][4];
    #pragma unroll
    for (int m = 0; m < 2; m++)
        #pragma unroll
        for (int tt = 0; tt < 4; tt++) acc[m][tt] = (f32x4){0.f, 0.f, 0.f, 0.f};

    #pragma unroll
    for (int ks = 0; ks < 4; ks++) {
        bf16x8 a0 = *(const bf16x8*)&sA[n15 * 136 + ks * 32 + q * 8];
        bf16x8 a1 = *(const bf16x8*)&sA[(16 + n15) * 136 + ks * 32 + q * 8];
        #pragma unroll
        for (int tt = 0; tt < 4; tt++) {
            int nt = (tt < 2) ? (2 * w + tt) : (8 + 2 * w + (tt - 2));
            bf16x8 b = *(const bf16x8*)(bfrag + ((size_t)(nt * 4 + ks) * 64 + lane) * 8);
            acc[0][tt] = __builtin_amdgcn_mfma_f32_16x16x32_bf16(a0, b, acc[0][tt], 0, 0, 0);
            acc[1][tt] = __builtin_amdgcn_mfma_f32_16x16x32_bf16(a1, b, acc[1][tt], 0, 0, 0);
        }
    }

    // el/er for head w (all waves busy)
    {
        float al0 = attn_l[w * 32 + n15];
        float al1 = attn_l[w * 32 + 16 + n15];
        float ar0 = attn_r[w * 32 + n15];
        float ar1 = attn_r[w * 32 + 16 + n15];
        #pragma unroll
        for (int m = 0; m < 2; m++) {
            #pragma unroll
            for (int r = 0; r < 4; r++) {
                float fa = acc[m][0][r], fb = acc[m][1][r];
                float elp = fa * al0 + fb * al1;
                float erp = fa * ar0 + fb * ar1;
                elp += __shfl_xor(elp, 1); erp += __shfl_xor(erp, 1);
                elp += __shfl_xor(elp, 2); erp += __shfl_xor(erp, 2);
                elp += __shfl_xor(elp, 4); erp += __shfl_xor(erp, 4);
                elp += __shfl_xor(elp, 8); erp += __shfl_xor(erp, 8);
                int node = nb + m * 16 + q * 4 + r;
                if (n15 == 0 && node < V_N) {
                    el[node * 4 + w] = elp;
                    er[node * 4 + w] = erp;
                }
            }
        }
    }
    // ft f16 store, head-major: uint idx = node*64 + w*16 + n15
    #pragma unroll
    for (int m = 0; m < 2; m++)
        #pragma unroll
        for (int r = 0; r < 4; r++) {
            int node = nb + m * 16 + q * 4 + r;
            if (node < V_N)
                ftw[(size_t)node * 64 + w * 16 + n15] =
                    pkh2(acc[m][0][r], acc[m][1][r]);
        }
    __syncthreads();

    // residual: wave w stages cols 32w..32w+31 (tt=2,3)
    #pragma unroll
    for (int m = 0; m < 2; m++)
        #pragma unroll
        for (int tt = 2; tt < 4; tt++)
            #pragma unroll
            for (int r = 0; r < 4; r++)
                sSf[(m * 16 + q * 4 + r) * 140 + w * 32 + (tt - 2) * 16 + n15] =
                    acc[m][tt][r];
    __syncthreads();
    #pragma unroll
    for (int i = 0; i < 4; i++) {
        int u = t + i * 256;
        int node = u >> 5, c4 = (u & 31) * 4;
        if (nb + node < V_N) {
            float4 v = *(float4*)&sSf[node * 140 + c4];
            float4 b4 = *(const float4*)(bias + c4);
            v.x += b4.x; v.y += b4.y; v.z += b4.z; v.w += b4.w;
            *(float4*)(out + (size_t)(nb + node) * HF + c4) = v;
        }
    }
}

// K3: bin. 512 edges/block (1563 blocks -> ~6/CU). Stage all ee in LDS with
// ONE barrier, then 2 independent edges/thread: LDS-cursor scatter to recb.
// Cursor row H[b*NBUCKET + t] is contiguous (coalesced load).
__global__ __launch_bounds__(256) void k_bin(
    const float* __restrict__ ef, const int* __restrict__ src,
    const int* __restrict__ dst, const float* __restrict__ watt,
    const float* __restrict__ el, const int* __restrict__ H,
    uint4* __restrict__ recb)
{
    __shared__ float sw[64];
    __shared__ __align__(16) float see[PSZ][4];
    __shared__ int boff[NBUCKET];
    const int t = threadIdx.x;
    const int b = blockIdx.x;
    if (t < 64) sw[t] = watt[t];
    if (t < NBUCKET) boff[t] = H[b * NBUCKET + t];
    __syncthreads();
    const int lane = t & 63, w = t >> 6;
    const int k0 = (lane & 3) * 4;

    // phase 1: quad (4 lanes) per edge; lane reads 16B of the 64B ef row
    #pragma unroll
    for (int r = 0; r < 8; r++) {
        int le = w * 128 + r * 16 + (lane >> 2);    // local edge 0..511
        int ge = b * PSZ + le;
        float4 v = {0.f, 0.f, 0.f, 0.f};
        if (ge < E_N)
            v = *(const float4*)(ef + (size_t)ge * EDGE_IN + k0);
        float e0 = 0.f, e1 = 0.f, e2 = 0.f, e3 = 0.f;
        float vv[4] = {v.x, v.y, v.z, v.w};
        #pragma unroll
        for (int j = 0; j < 4; j++) {
            int k = k0 + j;
            e0 += vv[j] * sw[k * 4 + 0];
            e1 += vv[j] * sw[k * 4 + 1];
            e2 += vv[j] * sw[k * 4 + 2];
            e3 += vv[j] * sw[k * 4 + 3];
        }
        e0 += __shfl_xor(e0, 1); e1 += __shfl_xor(e1, 1);
        e2 += __shfl_xor(e2, 1); e3 += __shfl_xor(e3, 1);
        e0 += __shfl_xor(e0, 2); e1 += __shfl_xor(e1, 2);
        e2 += __shfl_xor(e2, 2); e3 += __shfl_xor(e3, 2);
        if ((lane & 3) == 0) {
            float4 o = {e0, e1, e2, e3};
            *(float4*)&see[le][0] = o;
        }
    }
    __syncthreads();

    // phase 2: 2 independent edges/thread
    #pragma unroll
    for (int c = 0; c < 2; c++) {
        int le = c * 256 + t;
        int e = b * PSZ + le;
        if (e < E_N) {
            int s = src[e], d = dst[e];
            int p = atomicAdd(&boff[d >> 8], 1);
            float4 ee = *(float4*)&see[le][0];
            float4 el4 = *(const float4*)(el + (size_t)s * 4);
            uint4 rr;
            rr.x = (unsigned)s;
            rr.y = pk2(el4.x + ee.x, el4.y + ee.y);
            rr.z = pk2(el4.z + ee.z, el4.w + ee.w);
            rr.w = (unsigned)d;
            recb[p] = rr;
        }
    }
}

// K4: group. One block per bucket (256 dsts): global base from binsum prefix
// (redundant per-block, <=196 L2-hot ints), LDS count + scan over the
// bucket's records, write rowp, permute records to compact dst-grouped rec.
__global__ __launch_bounds__(256) void k_group(
    const int* __restrict__ binsum, const uint4* __restrict__ recb,
    uint4* __restrict__ rec, int* __restrict__ rowp)
{
    __shared__ int cnt[256];
    __shared__ int s1[256];
    __shared__ int cur[256];
    const int t = threadIdx.x;
    const int b = blockIdx.x;

    // global base = sum binsum[0..b)
    int pre = 0;
    for (int i = t; i < b; i += 256) pre += binsum[i];
    s1[t] = pre;
    __syncthreads();
    #pragma unroll
    for (int off = 128; off > 0; off >>= 1) {
        if (t < off) s1[t] += s1[t + off];
        __syncthreads();
    }
    const int gbase = s1[0];
    const int size = binsum[b];
    const int src0 = b * CAP;
    __syncthreads();

    cnt[t] = 0;
    __syncthreads();
    const int* recw = (const int*)recb;
    for (int i = t; i < size; i += 256)
        atomicAdd(&cnt[recw[4 * (src0 + i) + 3] & 255], 1);
    __syncthreads();
    int v = cnt[t];
    s1[t] = v;
    __syncthreads();
    #pragma unroll
    for (int off = 1; off < 256; off <<= 1) {
        int u = (t >= off) ? s1[t - off] : 0;
        __syncthreads();
        s1[t] += u;
        __syncthreads();
    }
    int exc = s1[t] - v;
    int d = (b << 8) + t;
    if (d < V_N) rowp[d] = gbase + exc;
    if (b == 0 && t == 0) rowp[V_N] = E_N;
    cur[t] = gbase + exc;
    __syncthreads();
    for (int i = t; i < size; i += 256) {
        uint4 r = recb[src0 + i];
        int dl = (int)(r.w & 255u);
        int p = atomicAdd(&cur[dl], 1);
        rec[p] = r;
    }
}

// K5: gather, 16-lane group per dst (avg deg = 16). 16 groups/block,
// 50000 = 3125*16 exactly. Each lane li owns 8 f16 output cols across ALL
// edges -> no cross-lane U reduction. s (denominator) reduced over 16 lanes.
__global__ __launch_bounds__(256) void k_gather(
    const int* __restrict__ row, const uint4* __restrict__ rec,
    const float* __restrict__ er,
    const unsigned* __restrict__ ftw, float* __restrict__ out)
{
    __shared__ unsigned aw[16][16][4];   // [group][edge][head] dup-half2 ex
    const int t = threadIdx.x;
    const int g = t >> 4;                // group in block
    const int li = t & 15;
    const int head = li >> 2;
    const int lanebase = t & 48;         // group base within the wave
    const int d = blockIdx.x * 16 + g;
    const int n0 = row[d];
    const int deg = row[d + 1] - n0;
    if (deg == 0) return;

    const float4 er4 = *(const float4*)(er + (size_t)d * 4);
    float4 s4 = {0.f, 0.f, 0.f, 0.f};
    __half2 ha0 = u2h(0u), ha1 = u2h(0u), ha2 = u2h(0u), ha3 = u2h(0u);
    __half2 hb0 = u2h(0u), hb1 = u2h(0u), hb2 = u2h(0u), hb3 = u2h(0u);

    for (int i0 = 0; i0 < deg; i0 += 16) {
        int chunk = min(16, deg - i0);
        int si = 0;
        float4 ex = {0.f, 0.f, 0.f, 0.f};
        if (li < chunk) {
            uint4 r = rec[n0 + i0 + li];
            si = (int)r.x;
            float x0 = bflo(r.y) + er4.x;
            float x1 = bfhi(r.y) + er4.y;
            float x2 = bflo(r.z) + er4.z;
            float x3 = bfhi(r.z) + er4.w;
            x0 = x0 >= 0.f ? x0 : NEG_SLOPE * x0;
            x1 = x1 >= 0.f ? x1 : NEG_SLOPE * x1;
            x2 = x2 >= 0.f ? x2 : NEG_SLOPE * x2;
            x3 = x3 >= 0.f ? x3 : NEG_SLOPE * x3;
            ex.x = __expf(x0); ex.y = __expf(x1);
            ex.z = __expf(x2); ex.w = __expf(x3);
            s4.x += ex.x; s4.y += ex.y; s4.z += ex.z; s4.w += ex.w;
        }
        uint4 ap;
        ap.x = pkh2(ex.x, ex.x); ap.y = pkh2(ex.y, ex.y);
        ap.z = pkh2(ex.z, ex.z); ap.w = pkh2(ex.w, ex.w);
        *(uint4*)&aw[g][li][0] = ap;
        asm volatile("s_waitcnt lgkmcnt(0)" ::: "memory");

        int ce = (chunk + 1) & ~1;       // odd tail edge has ex=0,si=0 -> safe
        for (int j = 0; j < ce; j += 2) {
            int s0 = __shfl(si, lanebase + j);
            int s1v = __shfl(si, lanebase + j + 1);
            unsigned a0 = aw[g][j][head];
            unsigned a1 = aw[g][j + 1][head];
            uint4 w0 = *(const uint4*)(ftw + (size_t)s0 * 64 + li * 4);
            uint4 w1 = *(const uint4*)(ftw + (size_t)s1v * 64 + li * 4);
            ha0 = __hfma2(u2h(w0.x), u2h(a0), ha0);
            ha1 = __hfma2(u2h(w0.y), u2h(a0), ha1);
            ha2 = __hfma2(u2h(w0.z), u2h(a0), ha2);
            ha3 = __hfma2(u2h(w0.w), u2h(a0), ha3);
            hb0 = __hfma2(u2h(w1.x), u2h(a1), hb0);
            hb1 = __hfma2(u2h(w1.y), u2h(a1), hb1);
            hb2 = __hfma2(u2h(w1.z), u2h(a1), hb2);
            hb3 = __hfma2(u2h(w1.w), u2h(a1), hb3);
        }
    }
    // denominator: reduce s4 over the 16-lane group
    #pragma unroll
    for (int off = 1; off < 16; off <<= 1) {
        s4.x += __shfl_xor(s4.x, off);
        s4.y += __shfl_xor(s4.y, off);
        s4.z += __shfl_xor(s4.z, off);
        s4.w += __shfl_xor(s4.w, off);
    }
    ha0 = __hadd2(ha0, hb0); ha1 = __hadd2(ha1, hb1);
    ha2 = __hadd2(ha2, hb2); ha3 = __hadd2(ha3, hb3);

    float rsv = 1.f / (head == 0 ? s4.x : head == 1 ? s4.y :
                       head == 2 ? s4.z : s4.w);
    // lane li: cols head*32 + (li&3)*4 + {0..3} and +16
    float* op = out + (size_t)d * HF + head * 32 + (li & 3) * 4;
    float4 r0 = *(float4*)op;
    r0.x += __low2float(ha0) * rsv; r0.y += __low2float(ha1) * rsv;
    r0.z += __low2float(ha2) * rsv; r0.w += __low2float(ha3) * rsv;
    *(float4*)op = r0;
    float4 r1 = *(float4*)(op + 16);
    r1.x += __high2float(ha0) * rsv; r1.y += __high2float(ha1) * rsv;
    r1.z += __high2float(ha2) * rsv; r1.w += __high2float(ha3) * rsv;
    *(float4*)(op + 16) = r1;
}

extern "C" void kernel_launch(void* const* d_in, const int* in_sizes, int n_in,
                              void* d_out, int out_size, void* d_ws, size_t ws_size,
                              hipStream_t stream) {
    const float* nf     = (const float*)d_in[0];
    const float* ef     = (const float*)d_in[1];
    const int*   src    = (const int*)d_in[2];
    const int*   dst    = (const int*)d_in[3];
    const float* Wn     = (const float*)d_in[4];
    const float* We     = (const float*)d_in[5];
    const float* attn_l = (const float*)d_in[6];
    const float* attn_r = (const float*)d_in[7];
    const float* attn_e = (const float*)d_in[8];
    const float* Wr     = (const float*)d_in[9];
    const float* bias   = (const float*)d_in[10];
    float* out = (float*)d_out;

    unsigned* wsw  = (unsigned*)d_ws;
    unsigned* ftw  = wsw + OFF_FT;
    float* el      = (float*)(wsw + OFF_EL);
    float* er      = (float*)(wsw + OFF_ER);
    int* rowp      = (int*)(wsw + OFF_ROW);
    int* H         = (int*)(wsw + OFF_H);
    int* binsum    = (int*)(wsw + OFF_BSUM);
    float* watt    = (float*)(wsw + OFF_WATT);
    unsigned* bfrag = wsw + OFF_BFRAG;
    uint4* recb    = (uint4*)(wsw + OFF_RECB);
    uint4* rec     = (uint4*)(wsw + OFF_REC);

    k_prephist<<<PREP_BLKS + NPART, 256, 0, stream>>>(
        We, attn_e, Wn, Wr, dst, watt, bfrag, H);
    k_nodescan<<<NBUCKET + NODE_BLKS, 256, 0, stream>>>(
        nf, bfrag, attn_l, attn_r, bias, ftw, el, er, out, H, binsum);
    k_bin<<<NPART, 256, 0, stream>>>(ef, src, dst, watt, el, H, recb);
    k_group<<<NBUCKET, 256, 0, stream>>>(binsum, recb, rec, rowp);
    k_gather<<<V_N / 16, 256, 0, stream>>>(rowp, rec, er, ftw, out);
}